// Round 2
// baseline (5572.741 us; speedup 1.0000x reference)
//
#include <hip/hip_runtime.h>
#include <stdint.h>

// ============================================================================
// KOSS_34265249087558 — 2-layer Mamba-ish block on MI355X (gfx950)
// Round 1: fit workspace under 256 MiB (suspected cause of round-0 GPU fault).
//   - fp16 storage for xs_pre/delta, xs, z, y, gated (fp32 compute throughout)
//   - h3 overlays dead w_in region; kerr+h1 overlay dead xn region
//   - removed round-0 stray gate_k (OOB-into-delta bug)
//   - all big GEMMs: fp16 MFMA 16x16x32, NT, XOR-swizzled LDS
// Workspace need: 248,578,048 B (~237.1 MiB)
// ============================================================================

#define B_    4
#define L_    2048
#define DM_   1024
#define ED_   2048
#define SEG_  256
#define NSEG_ 8
#define CH_   16   // scan chunks per segment
#define TS_   16   // steps per chunk  (CH_*TS_ == SEG_)

typedef _Float16 f16x8 __attribute__((ext_vector_type(8)));
typedef _Float16 f16x4 __attribute__((ext_vector_type(4)));
typedef float    f32x4 __attribute__((ext_vector_type(4)));

__device__ __forceinline__ float siluf(float x)     { return x / (1.0f + expf(-x)); }
__device__ __forceinline__ float softplusf(float x) { return (x > 20.0f) ? x : log1pf(expf(x)); }

// ---------------------------------------------------------------------------
// fp32 -> fp16 conversion (vector x4)
// ---------------------------------------------------------------------------
__global__ void f2h_kernel(const float* __restrict__ in, _Float16* __restrict__ out, int n4) {
    int i = blockIdx.x * 256 + threadIdx.x;
    if (i < n4) {
        float4 v = ((const float4*)in)[i];
        f16x4 h;
        h[0] = (_Float16)v.x; h[1] = (_Float16)v.y;
        h[2] = (_Float16)v.z; h[3] = (_Float16)v.w;
        ((f16x4*)out)[i] = h;
    }
}

// ---------------------------------------------------------------------------
// RMSNorm: one block per row (B*L rows, DM cols), writes fp16
// ---------------------------------------------------------------------------
__global__ __launch_bounds__(256) void rmsnorm_k(const float* __restrict__ H,
                                                 const float* __restrict__ w,
                                                 _Float16* __restrict__ out) {
    __shared__ float sred[4];
    int row = blockIdx.x;
    const float* h = H + (size_t)row * DM_;
    float ss = 0.f;
    for (int c = threadIdx.x; c < DM_; c += 256) { float v = h[c]; ss += v * v; }
    for (int off = 32; off; off >>= 1) ss += __shfl_down(ss, off, 64);
    if ((threadIdx.x & 63) == 0) sred[threadIdx.x >> 6] = ss;
    __syncthreads();
    float tot = sred[0] + sred[1] + sred[2] + sred[3];
    float scale = rsqrtf(tot * (1.0f / DM_) + 1e-5f);
    for (int c = threadIdx.x; c < DM_; c += 256)
        out[(size_t)row * DM_ + c] = (_Float16)(h[c] * scale * w[c]);
}

// ---------------------------------------------------------------------------
// MFMA GEMM, NT: C[m,n] = sum_k A[m,k] * Bw[n,k]   (A,Bw fp16, acc fp32)
// EPI: 0 fp32 store (outf); 1 split halves -> fp16 outh | outh2;
//      2 bias+relu -> fp16 outh; 3 relu -> fp16 outh; 4 outf = addsrc + acc
// ---------------------------------------------------------------------------
template<int BM, int BN, int WR, int WC, int EPI>
__global__ __launch_bounds__(256, 2)
void gemm_nt(const _Float16* __restrict__ A, const _Float16* __restrict__ Bw,
             int K, int N,
             float* outf, _Float16* __restrict__ outh, _Float16* __restrict__ outh2,
             const float* __restrict__ bias, const float* addsrc) {
    constexpr int WTM = BM / (16 * WR);
    constexpr int WTN = BN / (16 * WC);
    constexpr int NA = BM * 4 / 256;   // 16B chunks per thread for A tile
    constexpr int NB = BN * 4 / 256;
    static_assert(BM * 4 % 256 == 0 && BN * 4 % 256 == 0, "tile");

    __shared__ __align__(16) _Float16 lsA[BM * 32];
    __shared__ __align__(16) _Float16 lsB[BN * 32];

    const int tid  = threadIdx.x;
    const int lane = tid & 63;
    const int wid  = tid >> 6;
    const int wm   = wid / WC, wn = wid % WC;
    const int m0   = blockIdx.y * BM, n0 = blockIdx.x * BN;

    f32x4 acc[WTM][WTN];
#pragma unroll
    for (int i = 0; i < WTM; ++i)
#pragma unroll
        for (int j = 0; j < WTN; ++j) acc[i][j] = (f32x4){0.f, 0.f, 0.f, 0.f};

    for (int k0 = 0; k0 < K; k0 += 32) {
        f16x8 ra[NA], rb[NB];
#pragma unroll
        for (int it = 0; it < NA; ++it) {
            int c = tid + 256 * it;
            int row = c >> 2, q = c & 3;
            int kc = q ^ ((row >> 1) & 3);                 // XOR swizzle (bank spread)
            ra[it] = *(const f16x8*)(A + (size_t)(m0 + row) * K + k0 + kc * 8);
        }
#pragma unroll
        for (int it = 0; it < NB; ++it) {
            int c = tid + 256 * it;
            int row = c >> 2, q = c & 3;
            int kc = q ^ ((row >> 1) & 3);
            rb[it] = *(const f16x8*)(Bw + (size_t)(n0 + row) * K + k0 + kc * 8);
        }
        __syncthreads();   // previous iteration's LDS reads complete
#pragma unroll
        for (int it = 0; it < NA; ++it) { int c = tid + 256 * it; *(f16x8*)&lsA[c * 8] = ra[it]; }
#pragma unroll
        for (int it = 0; it < NB; ++it) { int c = tid + 256 * it; *(f16x8*)&lsB[c * 8] = rb[it]; }
        __syncthreads();

        f16x8 af[WTM], bfr[WTN];
#pragma unroll
        for (int i = 0; i < WTM; ++i) {
            int row = wm * (WTM * 16) + i * 16 + (lane & 15);
            int q = (lane >> 4) ^ ((row >> 1) & 3);
            af[i] = *(const f16x8*)&lsA[row * 32 + q * 8];
        }
#pragma unroll
        for (int j = 0; j < WTN; ++j) {
            int row = wn * (WTN * 16) + j * 16 + (lane & 15);
            int q = (lane >> 4) ^ ((row >> 1) & 3);
            bfr[j] = *(const f16x8*)&lsB[row * 32 + q * 8];
        }
#pragma unroll
        for (int i = 0; i < WTM; ++i)
#pragma unroll
            for (int j = 0; j < WTN; ++j)
                acc[i][j] = __builtin_amdgcn_mfma_f32_16x16x32_f16(af[i], bfr[j], acc[i][j], 0, 0, 0);
    }

    // epilogue: C/D layout col=lane&15, row=(lane>>4)*4+reg  [verified m89/m91]
#pragma unroll
    for (int i = 0; i < WTM; ++i) {
#pragma unroll
        for (int j = 0; j < WTN; ++j) {
            int mb = m0 + wm * (WTM * 16) + i * 16 + ((lane >> 4) * 4);
            int nb = n0 + wn * (WTN * 16) + j * 16 + (lane & 15);
#pragma unroll
            for (int r = 0; r < 4; ++r) {
                float v = acc[i][j][r];
                int m = mb + r;
                size_t o = (size_t)m * N + nb;
                if (EPI == 0) {
                    outf[o] = v;
                } else if (EPI == 1) {
                    int half = N >> 1;
                    if (nb < half) outh [(size_t)m * half + nb]          = (_Float16)v;
                    else           outh2[(size_t)m * half + (nb - half)] = (_Float16)v;
                } else if (EPI == 2) {
                    v += bias[nb]; v = fmaxf(v, 0.f); outh[o] = (_Float16)v;
                } else if (EPI == 3) {
                    v = fmaxf(v, 0.f); outh[o] = (_Float16)v;
                } else if (EPI == 4) {
                    outf[o] = addsrc[o] + v;
                }
            }
        }
    }
}

// ---------------------------------------------------------------------------
// fused causal dwconv(2 taps) x2 + SiLU : xs_pre(fp16) -> xs(fp16)
// ---------------------------------------------------------------------------
__global__ void convsilu_k(const _Float16* __restrict__ xp,
                           const float* __restrict__ c1w, const float* __restrict__ c1b,
                           const float* __restrict__ c2w, const float* __restrict__ c2b,
                           _Float16* __restrict__ xs, int layer) {
    size_t idx = (size_t)blockIdx.x * 256 + threadIdx.x;  // over B*L*ED
    int e = (int)(idx % ED_);
    size_t bl = idx / ED_;
    int l = (int)(bl % L_);
    size_t wb = (size_t)layer * ED_ + e;
    float w10 = c1w[wb * 2], w11 = c1w[wb * 2 + 1], b1 = c1b[wb];
    float w20 = c2w[wb * 2], w21 = c2w[wb * 2 + 1], b2 = c2b[wb];
    float x0  = (float)xp[idx];
    float xm1 = (l >= 1) ? (float)xp[idx - ED_] : 0.f;
    float xm2 = (l >= 2) ? (float)xp[idx - 2 * ED_] : 0.f;
    float s1  = b1 + w10 * xm1 + w11 * x0;
    float s1m = (l >= 1) ? (b1 + w10 * xm2 + w11 * xm1) : 0.f;
    float s2  = b2 + w20 * s1m + w21 * s1;
    xs[idx] = (_Float16)siluf(s2);
}

// ---------------------------------------------------------------------------
// dC = xs @ xp_w[i].T  (M=8192, N=66, K=2048) — one wave per row
// ---------------------------------------------------------------------------
__global__ __launch_bounds__(256) void gemv_dc(const _Float16* __restrict__ xs,
                                               const float* __restrict__ xp_w,
                                               float* __restrict__ dC, int layer) {
    int row  = blockIdx.x * 4 + (threadIdx.x >> 6);
    int lane = threadIdx.x & 63;
    const _Float16* xr = xs + (size_t)row * ED_;
    float xrow[32];
#pragma unroll
    for (int c = 0; c < 32; ++c) xrow[c] = (float)xr[c * 64 + lane];
    const float* W = xp_w + (size_t)layer * 66 * ED_;
    for (int j = 0; j < 66; ++j) {
        const float* wj = W + (size_t)j * ED_;
        float p = 0.f;
#pragma unroll
        for (int c = 0; c < 32; ++c) p += xrow[c] * wj[c * 64 + lane];
        for (int off = 32; off; off >>= 1) p += __shfl_down(p, off, 64);
        if (lane == 0) dC[(size_t)row * 66 + j] = p;
    }
}

// ---------------------------------------------------------------------------
// delta = softplus(dr @ dt_w.T + dt_b) -> fp16  (M=8192, N=2048, K=64)
// ---------------------------------------------------------------------------
__global__ __launch_bounds__(256) void delta_k(const float* __restrict__ dC,
                                               const float* __restrict__ dt_w,
                                               const float* __restrict__ dt_b,
                                               _Float16* __restrict__ delta, int layer) {
    __shared__ float dr[64];
    int row = blockIdx.y;
    int col = blockIdx.x * 256 + threadIdx.x;
    if (threadIdx.x < 64) dr[threadIdx.x] = dC[(size_t)row * 66 + threadIdx.x];
    __syncthreads();
    const float* w = dt_w + ((size_t)layer * ED_ + col) * 64;
    float acc = dt_b[(size_t)layer * ED_ + col];
#pragma unroll
    for (int k = 0; k < 64; k += 4) {
        float4 wv = *(const float4*)&w[k];
        acc += dr[k] * wv.x + dr[k + 1] * wv.y + dr[k + 2] * wv.z + dr[k + 3] * wv.w;
    }
    delta[(size_t)row * ED_ + col] = (_Float16)softplusf(acc);
}

// ---------------------------------------------------------------------------
// Kerr = soft_sign((xg - yh)^2) -> fp16  (yh = previous segment of y, 0 at s0=0)
// ---------------------------------------------------------------------------
__global__ void kerr_k(const _Float16* __restrict__ xs, const _Float16* __restrict__ y,
                       _Float16* __restrict__ kerr, int s0) {
    size_t idx = (size_t)blockIdx.x * 256 + threadIdx.x;  // over B*SEG*ED
    int e = (int)(idx % ED_);
    size_t bt = idx / ED_;
    int t = (int)(bt % SEG_);
    int b = (int)(bt / SEG_);
    size_t gx = ((size_t)(b * L_ + s0 + t)) * ED_ + e;
    float xg = (float)xs[gx];
    float yh = (s0 == 0) ? 0.f : (float)y[gx - (size_t)SEG_ * ED_];
    float d = xg - yh;
    float s = d * d;
    kerr[idx] = (_Float16)(s / (1.f + s));
}

// ---------------------------------------------------------------------------
// layernorm(h3) -> Knew ; K = (1-alpha)K + alpha*Knew   (one block per row)
// ---------------------------------------------------------------------------
__global__ __launch_bounds__(256) void ln_ema_k(const float* __restrict__ h3,
                                                const float* __restrict__ ln_g,
                                                const float* __restrict__ ln_b,
                                                const float* __restrict__ k_alpha,
                                                float* __restrict__ K, int layer) {
    __shared__ float sred[4];
    int row = blockIdx.x;  // b*SEG + t
    const float* hr = h3 + (size_t)row * ED_;
    float s = 0.f;
    for (int c = threadIdx.x; c < ED_; c += 256) s += hr[c];
    for (int off = 32; off; off >>= 1) s += __shfl_down(s, off, 64);
    if ((threadIdx.x & 63) == 0) sred[threadIdx.x >> 6] = s;
    __syncthreads();
    float mu = (sred[0] + sred[1] + sred[2] + sred[3]) * (1.0f / ED_);
    __syncthreads();
    float v = 0.f;
    for (int c = threadIdx.x; c < ED_; c += 256) { float d = hr[c] - mu; v += d * d; }
    for (int off = 32; off; off >>= 1) v += __shfl_down(v, off, 64);
    if ((threadIdx.x & 63) == 0) sred[threadIdx.x >> 6] = v;
    __syncthreads();
    float var = (sred[0] + sred[1] + sred[2] + sred[3]) * (1.0f / ED_);
    float rstd = rsqrtf(var + 1e-5f);
    for (int c = threadIdx.x; c < ED_; c += 256) {
        size_t wb = (size_t)layer * ED_ + c;
        float kn = ln_g[wb] * (hr[c] - mu) * rstd + ln_b[wb];
        float al = fminf(fmaxf(k_alpha[wb], 0.01f), 0.99f);
        size_t ki = (size_t)row * ED_ + c;
        K[ki] = (1.f - al) * K[ki] + al * kn;
    }
}

// ---------------------------------------------------------------------------
// _fdu + Kdy: per (b,e): d = Re(IFFT( i*2*pi*f*g/(dt[k]+1e-5) * FFT(xg) ));
// Kdy = K * d.  Radix-2 FFT-256 in LDS; 16 channels per block.
// fwd DIF (natural->bitrev), multiplier at k=brev(p), inv DIT (bitrev->natural)
// NB: reference broadcasts dt over the FREQUENCY axis -> dt at time index k.
// ---------------------------------------------------------------------------
__global__ __launch_bounds__(256) void fdu_kdy_k(const _Float16* __restrict__ xs,
                                                 const _Float16* __restrict__ delta,
                                                 const float* __restrict__ K,
                                                 float* __restrict__ Kdy,
                                                 const float* __restrict__ sigma,
                                                 int layer, int s0) {
    __shared__ float re[SEG_ * 16];
    __shared__ float im[SEG_ * 16];
    __shared__ float twc[128], tws[128];
    const int tid = threadIdx.x;
    const int b   = blockIdx.x >> 7;          // 128 blocks per b (ED/16)
    const int e0  = (blockIdx.x & 127) * 16;
    float sg = sigma[layer];
    float sg2 = sg * sg;
    if (tid < 128) {
        float ang = -6.283185307179586f * (float)tid * (1.0f / 256.0f);
        twc[tid] = cosf(ang);
        tws[tid] = sinf(ang);   // = imag(e^{-i theta})
    }
    for (int ii = tid; ii < SEG_ * 16; ii += 256) {
        int t = ii >> 4, el = ii & 15;
        re[ii] = (float)xs[((size_t)(b * L_ + s0 + t)) * ED_ + e0 + el];
        im[ii] = 0.f;
    }
    __syncthreads();
    const int bb = tid >> 4;   // butterfly group base 0..15
    const int el = tid & 15;
    // forward DIF
#pragma unroll
    for (int ls = 7; ls >= 0; --ls) {
        int span = 1 << ls;
#pragma unroll
        for (int bi = 0; bi < 8; ++bi) {
            int bidx = bb + (bi << 4);            // 0..127
            int j    = bidx & (span - 1);
            int grp  = bidx >> ls;
            int p    = (grp << (ls + 1)) + j;
            int twi  = j << (7 - ls);
            int i0   = (p << 4) + el;
            int i1   = i0 + (span << 4);
            float ur = re[i0], ui = im[i0];
            float vr = re[i1], vi = im[i1];
            re[i0] = ur + vr; im[i0] = ui + vi;
            float dr = ur - vr, di = ui - vi;
            float c = twc[twi], sn = tws[twi];
            re[i1] = dr * c - di * sn;
            im[i1] = dr * sn + di * c;
        }
        __syncthreads();
    }
    // multiplier (bit-reversed position p holds X[brev(p)])
    for (int ii = tid; ii < SEG_ * 16; ii += 256) {
        int p = ii >> 4, ee = ii & 15;
        int k = __brev((unsigned)p) >> 24;
        float f = ((k < 128) ? (float)k : (float)(k - 256)) * (1.0f / 256.0f);
        float dt = (float)delta[((size_t)(b * L_ + s0 + k)) * ED_ + e0 + ee];
        float q = 6.283185307179586f * f * expf(-f * f * sg2) / (dt + 1e-5f);
        float xr = re[ii], xi = im[ii];
        re[ii] = -q * xi;     // i*q*(xr+ixi)
        im[ii] =  q * xr;
    }
    __syncthreads();
    // inverse DIT
#pragma unroll
    for (int ls = 0; ls <= 7; ++ls) {
        int span = 1 << ls;
#pragma unroll
        for (int bi = 0; bi < 8; ++bi) {
            int bidx = bb + (bi << 4);
            int j    = bidx & (span - 1);
            int grp  = bidx >> ls;
            int p    = (grp << (ls + 1)) + j;
            int twi  = j << (7 - ls);
            int i0   = (p << 4) + el;
            int i1   = i0 + (span << 4);
            float c = twc[twi], sn = -tws[twi];   // e^{+i theta}
            float vr = re[i1], vi = im[i1];
            float tr = vr * c - vi * sn;
            float ti = vr * sn + vi * c;
            float ur = re[i0], ui = im[i0];
            re[i0] = ur + tr; im[i0] = ui + ti;
            re[i1] = ur - tr; im[i1] = ui - ti;
        }
        __syncthreads();
    }
    for (int ii = tid; ii < SEG_ * 16; ii += 256) {
        int t = ii >> 4, ee = ii & 15;
        size_t ki = ((size_t)(b * SEG_ + t)) * ED_ + e0 + ee;
        Kdy[ki] = K[ki] * re[ii] * (1.0f / 256.0f);
    }
}

// ---------------------------------------------------------------------------
// scan coefficients (N=2 states), per element
// ---------------------------------------------------------------------------
__device__ __forceinline__ void scan_coefs(float dg, float xg, float Kt, float kdy,
                                           float C0, float C1, float A0, float A1,
                                           float& dA0, float& dB0, float& dA1, float& dB1) {
    float KC0 = Kt * C0;
    float AmK0 = A0 * (1.f - KC0);
    float Ak0 = AmK0 * (1.f + KC0);
    float Bk0 = -AmK0 * Kt;
    dA0 = expf(dg * Ak0);
    dB0 = dg * Bk0 * xg + kdy;
    float KC1 = Kt * C1;
    float AmK1 = A1 * (1.f - KC1);
    float Ak1 = AmK1 * (1.f + KC1);
    float Bk1 = -AmK1 * Kt;
    dA1 = expf(dg * Ak1);
    dB1 = dg * Bk1 * xg + kdy;
}

// pass A: per-chunk (prod, local-scan) pairs
__global__ void scanA_k(const _Float16* __restrict__ delta, const _Float16* __restrict__ xs,
                        const float* __restrict__ K, const float* __restrict__ Kdy,
                        const float* __restrict__ dC, const float* __restrict__ A_log,
                        float* __restrict__ P0, float* __restrict__ P1,
                        float* __restrict__ S0, float* __restrict__ S1,
                        int layer, int s0) {
    int e = blockIdx.x * 256 + threadIdx.x;
    int b = blockIdx.y >> 4;
    int c = blockIdx.y & 15;
    float A0 = -expf(A_log[((size_t)layer * ED_ + e) * 2 + 0]);
    float A1 = -expf(A_log[((size_t)layer * ED_ + e) * 2 + 1]);
    float p0 = 1.f, p1 = 1.f, s0v = 0.f, s1v = 0.f;
    for (int tt = 0; tt < TS_; ++tt) {
        int t = c * TS_ + tt;
        size_t gi = ((size_t)(b * L_ + s0 + t)) * ED_ + e;
        size_t ki = ((size_t)(b * SEG_ + t)) * ED_ + e;
        float dg = (float)delta[gi], xg = (float)xs[gi];
        float Kt = K[ki], kdy = Kdy[ki];
        size_t ci = (size_t)(b * L_ + s0 + t) * 66 + 64;
        float C0 = dC[ci], C1 = dC[ci + 1];
        float dA0, dB0, dA1, dB1;
        scan_coefs(dg, xg, Kt, kdy, C0, C1, A0, A1, dA0, dB0, dA1, dB1);
        p0 *= dA0; s0v = dA0 * s0v + dB0;
        p1 *= dA1; s1v = dA1 * s1v + dB1;
    }
    size_t si = ((size_t)(b * CH_ + c)) * ED_ + e;
    P0[si] = p0; P1[si] = p1; S0[si] = s0v; S1[si] = s1v;
}

// pass B: sequential combine across chunks -> carry-in per chunk (h resets per segment)
__global__ void scanB_k(const float* __restrict__ P0, const float* __restrict__ P1,
                        const float* __restrict__ S0, const float* __restrict__ S1,
                        float* __restrict__ Ca0, float* __restrict__ Ca1) {
    int t = blockIdx.x * 256 + threadIdx.x;  // B*ED
    int b = t / ED_, e = t % ED_;
    float h0 = 0.f, h1 = 0.f;
    for (int c = 0; c < CH_; ++c) {
        size_t si = ((size_t)(b * CH_ + c)) * ED_ + e;
        Ca0[si] = h0; Ca1[si] = h1;
        h0 = P0[si] * h0 + S0[si];
        h1 = P1[si] * h1 + S1[si];
    }
}

// pass C: re-run recurrence from carry-in, emit y = h.C + Dp*xg  (fp16 y)
__global__ void scanC_k(const _Float16* __restrict__ delta, const _Float16* __restrict__ xs,
                        const float* __restrict__ K, const float* __restrict__ Kdy,
                        const float* __restrict__ dC, const float* __restrict__ A_log,
                        const float* __restrict__ Dp,
                        const float* __restrict__ Ca0, const float* __restrict__ Ca1,
                        _Float16* __restrict__ y, int layer, int s0) {
    int e = blockIdx.x * 256 + threadIdx.x;
    int b = blockIdx.y >> 4;
    int c = blockIdx.y & 15;
    float A0 = -expf(A_log[((size_t)layer * ED_ + e) * 2 + 0]);
    float A1 = -expf(A_log[((size_t)layer * ED_ + e) * 2 + 1]);
    float Dpe = Dp[(size_t)layer * ED_ + e];
    size_t si = ((size_t)(b * CH_ + c)) * ED_ + e;
    float h0 = Ca0[si], h1 = Ca1[si];
    for (int tt = 0; tt < TS_; ++tt) {
        int t = c * TS_ + tt;
        size_t gi = ((size_t)(b * L_ + s0 + t)) * ED_ + e;
        size_t ki = ((size_t)(b * SEG_ + t)) * ED_ + e;
        float dg = (float)delta[gi], xg = (float)xs[gi];
        float Kt = K[ki], kdy = Kdy[ki];
        size_t ci = (size_t)(b * L_ + s0 + t) * 66 + 64;
        float C0 = dC[ci], C1 = dC[ci + 1];
        float dA0, dB0, dA1, dB1;
        scan_coefs(dg, xg, Kt, kdy, C0, C1, A0, A1, dA0, dB0, dA1, dB1);
        h0 = dA0 * h0 + dB0;
        h1 = dA1 * h1 + dB1;
        y[gi] = (_Float16)(h0 * C0 + h1 * C1 + Dpe * xg);
    }
}

// ---------------------------------------------------------------------------
// gate: g = y * silu(z) -> fp16
// ---------------------------------------------------------------------------
__global__ void gate_k(const _Float16* __restrict__ y, const _Float16* __restrict__ z,
                       _Float16* __restrict__ g) {
    size_t idx = (size_t)blockIdx.x * 256 + threadIdx.x;
    g[idx] = (_Float16)((float)y[idx] * siluf((float)z[idx]));
}

// ===========================================================================
// workspace layout (bytes) — total 248,578,048 (~237.1 MiB)
// ===========================================================================
#define OFF_WK1   ((size_t)0)                   // k1_w fp16            25165824
#define OFF_WK2   (OFF_WK1 + 25165824)          // k2_w fp16            25165824
#define OFF_WK3   (OFF_WK2 + 25165824)          // k3_w fp16             8388608
#define OFF_WOUT  (OFF_WK3 + 8388608)           // out_w fp16            4194304
#define OFF_WIN   (OFF_WOUT + 4194304)          // in_w fp16 / h3 fp32   8388608 (overlay)
#define OFF_XN    (OFF_WIN + 8388608)           // xn fp16 / kerr+h1    16777216 (overlay)
#define OFF_P     (OFF_XN + 16777216)           // xs_pre->delta->gated 33554432 (fp16)
#define OFF_XS    (OFF_P + 33554432)            // xs fp16              33554432
#define OFF_Z     (OFF_XS + 33554432)           // z fp16               33554432
#define OFF_Y     (OFF_Z + 33554432)            // y fp16               33554432
#define OFF_DC    (OFF_Y + 33554432)            // dC fp32               2162688
#define OFF_H2    (OFF_DC + 2162688)            // h2 fp16               4194304
#define OFF_K     (OFF_H2 + 4194304)            // K fp32                8388608
#define OFF_KDY   (OFF_K + 8388608)             // Kdy fp32              8388608
#define OFF_SP0   (OFF_KDY + 8388608)           // scan scratch 6x524288
#define OFF_SP1   (OFF_SP0 + 524288)
#define OFF_SS0   (OFF_SP1 + 524288)
#define OFF_SS1   (OFF_SS0 + 524288)
#define OFF_SC0   (OFF_SS1 + 524288)
#define OFF_SC1   (OFF_SC0 + 524288)
#define WS_NEED   (OFF_SC1 + 524288)

extern "C" void kernel_launch(void* const* d_in, const int* in_sizes, int n_in,
                              void* d_out, int out_size, void* d_ws, size_t ws_size,
                              hipStream_t stream) {
    if (ws_size < WS_NEED) return;  // deterministic clean failure (diagnostic) vs GPU fault

    const float* x_in   = (const float*)d_in[0];
    const float* rms_w  = (const float*)d_in[1];
    const float* in_w   = (const float*)d_in[2];
    const float* c1_w   = (const float*)d_in[3];
    const float* c1_b   = (const float*)d_in[4];
    const float* c2_w   = (const float*)d_in[5];
    const float* c2_b   = (const float*)d_in[6];
    const float* xp_w   = (const float*)d_in[7];
    const float* dt_w   = (const float*)d_in[8];
    const float* dt_b   = (const float*)d_in[9];
    const float* A_log  = (const float*)d_in[10];
    const float* Dp     = (const float*)d_in[11];
    const float* out_w  = (const float*)d_in[12];
    const float* k1_w   = (const float*)d_in[13];
    const float* k1_b   = (const float*)d_in[14];
    const float* k2_w   = (const float*)d_in[15];
    const float* k3_w   = (const float*)d_in[16];
    const float* ln_g   = (const float*)d_in[17];
    const float* ln_b   = (const float*)d_in[18];
    const float* k_alph = (const float*)d_in[19];
    const float* sigma  = (const float*)d_in[20];

    char* ws = (char*)d_ws;
    _Float16* w_k1  = (_Float16*)(ws + OFF_WK1);
    _Float16* w_k2  = (_Float16*)(ws + OFF_WK2);
    _Float16* w_k3  = (_Float16*)(ws + OFF_WK3);
    _Float16* w_out = (_Float16*)(ws + OFF_WOUT);
    _Float16* w_in  = (_Float16*)(ws + OFF_WIN);
    float*    h3buf = (float*)(ws + OFF_WIN);            // overlay (w_in dead by then)
    _Float16* xnbf  = (_Float16*)(ws + OFF_XN);
    _Float16* kerrb = (_Float16*)(ws + OFF_XN);          // overlay (xn dead)
    _Float16* h1bf  = (_Float16*)(ws + OFF_XN + 4194304);// overlay (xn dead)
    _Float16* xs_pre= (_Float16*)(ws + OFF_P);           // -> delta -> gated
    _Float16* xsbuf = (_Float16*)(ws + OFF_XS);
    _Float16* zbuf  = (_Float16*)(ws + OFF_Z);
    _Float16* ybuf  = (_Float16*)(ws + OFF_Y);
    float*    dCbuf = (float*)(ws + OFF_DC);
    _Float16* h2bf  = (_Float16*)(ws + OFF_H2);
    float*    Kbuf  = (float*)(ws + OFF_K);
    float*    Kdybuf= (float*)(ws + OFF_KDY);
    float* sP0 = (float*)(ws + OFF_SP0);
    float* sP1 = (float*)(ws + OFF_SP1);
    float* sS0 = (float*)(ws + OFF_SS0);
    float* sS1 = (float*)(ws + OFF_SS1);
    float* sC0 = (float*)(ws + OFF_SC0);
    float* sC1 = (float*)(ws + OFF_SC1);
    float* dout = (float*)d_out;
    _Float16* delta = xs_pre;   // alias: xs_pre dead after conv
    _Float16* gated = xs_pre;   // alias: delta dead after segment loop

    for (int layer = 0; layer < 2; ++layer) {
        hipMemsetAsync(Kbuf, 0, (size_t)B_ * SEG_ * ED_ * 4, stream);

        // convert this layer's weights to fp16
        f2h_kernel<<<4096, 256, 0, stream>>>(in_w  + (size_t)layer * 4194304,  w_in,  1048576);
        f2h_kernel<<<12288, 256, 0, stream>>>(k1_w + (size_t)layer * 12582912, w_k1,  3145728);
        f2h_kernel<<<12288, 256, 0, stream>>>(k2_w + (size_t)layer * 12582912, w_k2,  3145728);
        f2h_kernel<<<4096, 256, 0, stream>>>(k3_w  + (size_t)layer * 4194304,  w_k3,  1048576);
        f2h_kernel<<<2048, 256, 0, stream>>>(out_w + (size_t)layer * 2097152,  w_out, 524288);

        const float* Hsrc = (layer == 0) ? x_in : dout;
        rmsnorm_k<<<B_ * L_, 256, 0, stream>>>(Hsrc, rms_w + (size_t)layer * DM_, xnbf);

        // xz = xn @ in_w.T -> split xs_pre | z  (M=8192, N=4096, K=1024)
        gemm_nt<128, 128, 2, 2, 1><<<dim3(32, 64), 256, 0, stream>>>(
            xnbf, w_in, 1024, 4096, nullptr, xs_pre, zbuf, nullptr, nullptr);

        convsilu_k<<<65536, 256, 0, stream>>>(xs_pre, c1_w, c1_b, c2_w, c2_b, xsbuf, layer);

        gemv_dc<<<2048, 256, 0, stream>>>(xsbuf, xp_w, dCbuf, layer);

        delta_k<<<dim3(8, 8192), 256, 0, stream>>>(dCbuf, dt_w, dt_b, delta, layer);

        for (int s = 0; s < NSEG_; ++s) {
            int s0 = s * SEG_;
            kerr_k<<<8192, 256, 0, stream>>>(xsbuf, ybuf, kerrb, s0);
            // h1 = relu(Kerr @ k1.T + b1)  (1024 x 6144, K=2048)
            gemm_nt<128, 128, 2, 2, 2><<<dim3(48, 8), 256, 0, stream>>>(
                kerrb, w_k1, 2048, 6144, nullptr, h1bf, nullptr,
                k1_b + (size_t)layer * 6144, nullptr);
            // h2 = relu(h1 @ k2.T)  (1024 x 2048, K=6144)
            gemm_nt<64, 128, 1, 4, 3><<<dim3(16, 16), 256, 0, stream>>>(
                h1bf, w_k2, 6144, 2048, nullptr, h2bf, nullptr, nullptr, nullptr);
            // h3 = h2 @ k3.T  (1024 x 2048, K=2048) — fp32 into w_in overlay
            gemm_nt<64, 128, 1, 4, 0><<<dim3(16, 16), 256, 0, stream>>>(
                h2bf, w_k3, 2048, 2048, h3buf, nullptr, nullptr, nullptr, nullptr);
            ln_ema_k<<<B_ * SEG_, 256, 0, stream>>>(h3buf, ln_g, ln_b, k_alph, Kbuf, layer);
            fdu_kdy_k<<<B_ * (ED_ / 16), 256, 0, stream>>>(xsbuf, delta, Kbuf, Kdybuf,
                                                           sigma, layer, s0);
            scanA_k<<<dim3(ED_ / 256, B_ * CH_), 256, 0, stream>>>(
                delta, xsbuf, Kbuf, Kdybuf, dCbuf, A_log, sP0, sP1, sS0, sS1, layer, s0);
            scanB_k<<<(B_ * ED_) / 256, 256, 0, stream>>>(sP0, sP1, sS0, sS1, sC0, sC1);
            scanC_k<<<dim3(ED_ / 256, B_ * CH_), 256, 0, stream>>>(
                delta, xsbuf, Kbuf, Kdybuf, dCbuf, A_log, Dp, sC0, sC1, ybuf, layer, s0);
        }

        // gated = y * silu(z) -> fp16, into dead delta region
        gate_k<<<65536, 256, 0, stream>>>(ybuf, zbuf, gated);
        // out = gated @ out_w.T ; h = h_prev + out  (M=8192, N=1024, K=2048)
        gemm_nt<128, 128, 2, 2, 4><<<dim3(8, 64), 256, 0, stream>>>(
            gated, w_out, 2048, 1024, dout, nullptr, nullptr, nullptr,
            (layer == 0) ? x_in : dout);
    }
    (void)in_sizes; (void)n_in; (void)out_size;
}

// Round 3
// 4845.942 us; speedup vs baseline: 1.1500x; 1.1500x over previous
//
#include <hip/hip_runtime.h>
#include <stdint.h>

// ============================================================================
// KOSS_34265249087558 — 2-layer Mamba-ish block on MI355X (gfx950)
// Round 2 (prev passed: 5573 us, absmax 0.031):
//   - delta_k (494 us x2, 18% of total, MfmaUtil=0) -> MFMA GEMM K=64 (EPI=5)
//     dr emitted as fp16 by gemv_dc; dt_w converted to fp16 per layer
//   - gemm_nt staging: reg round-trip -> __builtin_amdgcn_global_load_lds w=16
//     (m93->m97 ladder step; LDS dest is lane-contiguous, swizzle on src addr)
// Workspace need: ~238.3 MiB
// ============================================================================

#define B_    4
#define L_    2048
#define DM_   1024
#define ED_   2048
#define SEG_  256
#define NSEG_ 8
#define CH_   16   // scan chunks per segment
#define TS_   16   // steps per chunk  (CH_*TS_ == SEG_)

typedef _Float16 f16x8 __attribute__((ext_vector_type(8)));
typedef _Float16 f16x4 __attribute__((ext_vector_type(4)));
typedef float    f32x4 __attribute__((ext_vector_type(4)));

__device__ __forceinline__ float siluf(float x)     { return x / (1.0f + expf(-x)); }
__device__ __forceinline__ float softplusf(float x) { return (x > 20.0f) ? x : log1pf(expf(x)); }

// async global->LDS, 16B per lane; LDS dest must be wave-uniform base + lane*16
#define GLD16(gptr, lptr)                                                     \
    __builtin_amdgcn_global_load_lds(                                         \
        (const __attribute__((address_space(1))) void*)(gptr),                \
        (__attribute__((address_space(3))) void*)(lptr), 16, 0, 0)

// ---------------------------------------------------------------------------
// fp32 -> fp16 conversion (vector x4)
// ---------------------------------------------------------------------------
__global__ void f2h_kernel(const float* __restrict__ in, _Float16* __restrict__ out, int n4) {
    int i = blockIdx.x * 256 + threadIdx.x;
    if (i < n4) {
        float4 v = ((const float4*)in)[i];
        f16x4 h;
        h[0] = (_Float16)v.x; h[1] = (_Float16)v.y;
        h[2] = (_Float16)v.z; h[3] = (_Float16)v.w;
        ((f16x4*)out)[i] = h;
    }
}

// ---------------------------------------------------------------------------
// RMSNorm: one block per row (B*L rows, DM cols), writes fp16
// ---------------------------------------------------------------------------
__global__ __launch_bounds__(256) void rmsnorm_k(const float* __restrict__ H,
                                                 const float* __restrict__ w,
                                                 _Float16* __restrict__ out) {
    __shared__ float sred[4];
    int row = blockIdx.x;
    const float* h = H + (size_t)row * DM_;
    float ss = 0.f;
    for (int c = threadIdx.x; c < DM_; c += 256) { float v = h[c]; ss += v * v; }
    for (int off = 32; off; off >>= 1) ss += __shfl_down(ss, off, 64);
    if ((threadIdx.x & 63) == 0) sred[threadIdx.x >> 6] = ss;
    __syncthreads();
    float tot = sred[0] + sred[1] + sred[2] + sred[3];
    float scale = rsqrtf(tot * (1.0f / DM_) + 1e-5f);
    for (int c = threadIdx.x; c < DM_; c += 256)
        out[(size_t)row * DM_ + c] = (_Float16)(h[c] * scale * w[c]);
}

// ---------------------------------------------------------------------------
// MFMA GEMM, NT: C[m,n] = sum_k A[m,k] * Bw[n,k]   (A,Bw fp16, acc fp32)
// EPI: 0 fp32 store (outf); 1 split halves -> fp16 outh | outh2;
//      2 bias+relu -> fp16 outh; 3 relu -> fp16 outh; 4 outf = addsrc + acc;
//      5 softplus(acc + bias) -> fp16 outh  (delta)
// ---------------------------------------------------------------------------
template<int BM, int BN, int WR, int WC, int EPI>
__global__ __launch_bounds__(256, 2)
void gemm_nt(const _Float16* __restrict__ A, const _Float16* __restrict__ Bw,
             int K, int N,
             float* outf, _Float16* __restrict__ outh, _Float16* __restrict__ outh2,
             const float* __restrict__ bias, const float* addsrc) {
    constexpr int WTM = BM / (16 * WR);
    constexpr int WTN = BN / (16 * WC);
    constexpr int NA = BM * 4 / 256;   // 16B chunks per thread for A tile
    constexpr int NB = BN * 4 / 256;
    static_assert(BM * 4 % 256 == 0 && BN * 4 % 256 == 0, "tile");

    __shared__ __align__(16) _Float16 lsA[BM * 32];
    __shared__ __align__(16) _Float16 lsB[BN * 32];

    const int tid  = threadIdx.x;
    const int lane = tid & 63;
    const int wid  = tid >> 6;
    const int wm   = wid / WC, wn = wid % WC;
    const int m0   = blockIdx.y * BM, n0 = blockIdx.x * BN;

    f32x4 acc[WTM][WTN];
#pragma unroll
    for (int i = 0; i < WTM; ++i)
#pragma unroll
        for (int j = 0; j < WTN; ++j) acc[i][j] = (f32x4){0.f, 0.f, 0.f, 0.f};

    for (int k0 = 0; k0 < K; k0 += 32) {
        __syncthreads();   // previous iteration's LDS reads complete
#pragma unroll
        for (int it = 0; it < NA; ++it) {
            int c = tid + 256 * it;
            int row = c >> 2, q = c & 3;
            int kc = q ^ ((row >> 1) & 3);                 // XOR swizzle (bank spread)
            GLD16(A + (size_t)(m0 + row) * K + k0 + kc * 8, &lsA[c * 8]);
        }
#pragma unroll
        for (int it = 0; it < NB; ++it) {
            int c = tid + 256 * it;
            int row = c >> 2, q = c & 3;
            int kc = q ^ ((row >> 1) & 3);
            GLD16(Bw + (size_t)(n0 + row) * K + k0 + kc * 8, &lsB[c * 8]);
        }
        __syncthreads();   // vmcnt(0) drained by compiler before barrier

        f16x8 af[WTM], bfr[WTN];
#pragma unroll
        for (int i = 0; i < WTM; ++i) {
            int row = wm * (WTM * 16) + i * 16 + (lane & 15);
            int q = (lane >> 4) ^ ((row >> 1) & 3);
            af[i] = *(const f16x8*)&lsA[row * 32 + q * 8];
        }
#pragma unroll
        for (int j = 0; j < WTN; ++j) {
            int row = wn * (WTN * 16) + j * 16 + (lane & 15);
            int q = (lane >> 4) ^ ((row >> 1) & 3);
            bfr[j] = *(const f16x8*)&lsB[row * 32 + q * 8];
        }
#pragma unroll
        for (int i = 0; i < WTM; ++i)
#pragma unroll
            for (int j = 0; j < WTN; ++j)
                acc[i][j] = __builtin_amdgcn_mfma_f32_16x16x32_f16(af[i], bfr[j], acc[i][j], 0, 0, 0);
    }

    // epilogue: C/D layout col=lane&15, row=(lane>>4)*4+reg  [verified m89/m91]
#pragma unroll
    for (int i = 0; i < WTM; ++i) {
#pragma unroll
        for (int j = 0; j < WTN; ++j) {
            int mb = m0 + wm * (WTM * 16) + i * 16 + ((lane >> 4) * 4);
            int nb = n0 + wn * (WTN * 16) + j * 16 + (lane & 15);
#pragma unroll
            for (int r = 0; r < 4; ++r) {
                float v = acc[i][j][r];
                int m = mb + r;
                size_t o = (size_t)m * N + nb;
                if (EPI == 0) {
                    outf[o] = v;
                } else if (EPI == 1) {
                    int half = N >> 1;
                    if (nb < half) outh [(size_t)m * half + nb]          = (_Float16)v;
                    else           outh2[(size_t)m * half + (nb - half)] = (_Float16)v;
                } else if (EPI == 2) {
                    v += bias[nb]; v = fmaxf(v, 0.f); outh[o] = (_Float16)v;
                } else if (EPI == 3) {
                    v = fmaxf(v, 0.f); outh[o] = (_Float16)v;
                } else if (EPI == 4) {
                    outf[o] = addsrc[o] + v;
                } else if (EPI == 5) {
                    v += bias[nb]; outh[o] = (_Float16)softplusf(v);
                }
            }
        }
    }
}

// ---------------------------------------------------------------------------
// fused causal dwconv(2 taps) x2 + SiLU : xs_pre(fp16) -> xs(fp16)
// ---------------------------------------------------------------------------
__global__ void convsilu_k(const _Float16* __restrict__ xp,
                           const float* __restrict__ c1w, const float* __restrict__ c1b,
                           const float* __restrict__ c2w, const float* __restrict__ c2b,
                           _Float16* __restrict__ xs, int layer) {
    size_t idx = (size_t)blockIdx.x * 256 + threadIdx.x;  // over B*L*ED
    int e = (int)(idx % ED_);
    size_t bl = idx / ED_;
    int l = (int)(bl % L_);
    size_t wb = (size_t)layer * ED_ + e;
    float w10 = c1w[wb * 2], w11 = c1w[wb * 2 + 1], b1 = c1b[wb];
    float w20 = c2w[wb * 2], w21 = c2w[wb * 2 + 1], b2 = c2b[wb];
    float x0  = (float)xp[idx];
    float xm1 = (l >= 1) ? (float)xp[idx - ED_] : 0.f;
    float xm2 = (l >= 2) ? (float)xp[idx - 2 * ED_] : 0.f;
    float s1  = b1 + w10 * xm1 + w11 * x0;
    float s1m = (l >= 1) ? (b1 + w10 * xm2 + w11 * xm1) : 0.f;
    float s2  = b2 + w20 * s1m + w21 * s1;
    xs[idx] = (_Float16)siluf(s2);
}

// ---------------------------------------------------------------------------
// dC = xs @ xp_w[i].T  (M=8192, N=66, K=2048) — one wave per row.
// Also emits dr (first 64 cols) as fp16 matrix [8192][64] for the delta GEMM.
// ---------------------------------------------------------------------------
__global__ __launch_bounds__(256) void gemv_dc(const _Float16* __restrict__ xs,
                                               const float* __restrict__ xp_w,
                                               float* __restrict__ dC,
                                               _Float16* __restrict__ dr16, int layer) {
    int row  = blockIdx.x * 4 + (threadIdx.x >> 6);
    int lane = threadIdx.x & 63;
    const _Float16* xr = xs + (size_t)row * ED_;
    float xrow[32];
#pragma unroll
    for (int c = 0; c < 32; ++c) xrow[c] = (float)xr[c * 64 + lane];
    const float* W = xp_w + (size_t)layer * 66 * ED_;
    for (int j = 0; j < 66; ++j) {
        const float* wj = W + (size_t)j * ED_;
        float p = 0.f;
#pragma unroll
        for (int c = 0; c < 32; ++c) p += xrow[c] * wj[c * 64 + lane];
        for (int off = 32; off; off >>= 1) p += __shfl_down(p, off, 64);
        if (lane == 0) {
            dC[(size_t)row * 66 + j] = p;
            if (j < 64) dr16[(size_t)row * 64 + j] = (_Float16)p;
        }
    }
}

// ---------------------------------------------------------------------------
// Kerr = soft_sign((xg - yh)^2) -> fp16  (yh = previous segment of y, 0 at s0=0)
// ---------------------------------------------------------------------------
__global__ void kerr_k(const _Float16* __restrict__ xs, const _Float16* __restrict__ y,
                       _Float16* __restrict__ kerr, int s0) {
    size_t idx = (size_t)blockIdx.x * 256 + threadIdx.x;  // over B*SEG*ED
    int e = (int)(idx % ED_);
    size_t bt = idx / ED_;
    int t = (int)(bt % SEG_);
    int b = (int)(bt / SEG_);
    size_t gx = ((size_t)(b * L_ + s0 + t)) * ED_ + e;
    float xg = (float)xs[gx];
    float yh = (s0 == 0) ? 0.f : (float)y[gx - (size_t)SEG_ * ED_];
    float d = xg - yh;
    float s = d * d;
    kerr[idx] = (_Float16)(s / (1.f + s));
}

// ---------------------------------------------------------------------------
// layernorm(h3) -> Knew ; K = (1-alpha)K + alpha*Knew   (one block per row)
// ---------------------------------------------------------------------------
__global__ __launch_bounds__(256) void ln_ema_k(const float* __restrict__ h3,
                                                const float* __restrict__ ln_g,
                                                const float* __restrict__ ln_b,
                                                const float* __restrict__ k_alpha,
                                                float* __restrict__ K, int layer) {
    __shared__ float sred[4];
    int row = blockIdx.x;  // b*SEG + t
    const float* hr = h3 + (size_t)row * ED_;
    float s = 0.f;
    for (int c = threadIdx.x; c < ED_; c += 256) s += hr[c];
    for (int off = 32; off; off >>= 1) s += __shfl_down(s, off, 64);
    if ((threadIdx.x & 63) == 0) sred[threadIdx.x >> 6] = s;
    __syncthreads();
    float mu = (sred[0] + sred[1] + sred[2] + sred[3]) * (1.0f / ED_);
    __syncthreads();
    float v = 0.f;
    for (int c = threadIdx.x; c < ED_; c += 256) { float d = hr[c] - mu; v += d * d; }
    for (int off = 32; off; off >>= 1) v += __shfl_down(v, off, 64);
    if ((threadIdx.x & 63) == 0) sred[threadIdx.x >> 6] = v;
    __syncthreads();
    float var = (sred[0] + sred[1] + sred[2] + sred[3]) * (1.0f / ED_);
    float rstd = rsqrtf(var + 1e-5f);
    for (int c = threadIdx.x; c < ED_; c += 256) {
        size_t wb = (size_t)layer * ED_ + c;
        float kn = ln_g[wb] * (hr[c] - mu) * rstd + ln_b[wb];
        float al = fminf(fmaxf(k_alpha[wb], 0.01f), 0.99f);
        size_t ki = (size_t)row * ED_ + c;
        K[ki] = (1.f - al) * K[ki] + al * kn;
    }
}

// ---------------------------------------------------------------------------
// _fdu + Kdy: per (b,e): d = Re(IFFT( i*2*pi*f*g/(dt[k]+1e-5) * FFT(xg) ));
// Kdy = K * d.  Radix-2 FFT-256 in LDS; 16 channels per block.
// fwd DIF (natural->bitrev), multiplier at k=brev(p), inv DIT (bitrev->natural)
// NB: reference broadcasts dt over the FREQUENCY axis -> dt at time index k.
// ---------------------------------------------------------------------------
__global__ __launch_bounds__(256) void fdu_kdy_k(const _Float16* __restrict__ xs,
                                                 const _Float16* __restrict__ delta,
                                                 const float* __restrict__ K,
                                                 float* __restrict__ Kdy,
                                                 const float* __restrict__ sigma,
                                                 int layer, int s0) {
    __shared__ float re[SEG_ * 16];
    __shared__ float im[SEG_ * 16];
    __shared__ float twc[128], tws[128];
    const int tid = threadIdx.x;
    const int b   = blockIdx.x >> 7;          // 128 blocks per b (ED/16)
    const int e0  = (blockIdx.x & 127) * 16;
    float sg = sigma[layer];
    float sg2 = sg * sg;
    if (tid < 128) {
        float ang = -6.283185307179586f * (float)tid * (1.0f / 256.0f);
        twc[tid] = cosf(ang);
        tws[tid] = sinf(ang);   // = imag(e^{-i theta})
    }
    for (int ii = tid; ii < SEG_ * 16; ii += 256) {
        int t = ii >> 4, el = ii & 15;
        re[ii] = (float)xs[((size_t)(b * L_ + s0 + t)) * ED_ + e0 + el];
        im[ii] = 0.f;
    }
    __syncthreads();
    const int bb = tid >> 4;   // butterfly group base 0..15
    const int el = tid & 15;
    // forward DIF
#pragma unroll
    for (int ls = 7; ls >= 0; --ls) {
        int span = 1 << ls;
#pragma unroll
        for (int bi = 0; bi < 8; ++bi) {
            int bidx = bb + (bi << 4);            // 0..127
            int j    = bidx & (span - 1);
            int grp  = bidx >> ls;
            int p    = (grp << (ls + 1)) + j;
            int twi  = j << (7 - ls);
            int i0   = (p << 4) + el;
            int i1   = i0 + (span << 4);
            float ur = re[i0], ui = im[i0];
            float vr = re[i1], vi = im[i1];
            re[i0] = ur + vr; im[i0] = ui + vi;
            float dr = ur - vr, di = ui - vi;
            float c = twc[twi], sn = tws[twi];
            re[i1] = dr * c - di * sn;
            im[i1] = dr * sn + di * c;
        }
        __syncthreads();
    }
    // multiplier (bit-reversed position p holds X[brev(p)])
    for (int ii = tid; ii < SEG_ * 16; ii += 256) {
        int p = ii >> 4, ee = ii & 15;
        int k = __brev((unsigned)p) >> 24;
        float f = ((k < 128) ? (float)k : (float)(k - 256)) * (1.0f / 256.0f);
        float dt = (float)delta[((size_t)(b * L_ + s0 + k)) * ED_ + e0 + ee];
        float q = 6.283185307179586f * f * expf(-f * f * sg2) / (dt + 1e-5f);
        float xr = re[ii], xi = im[ii];
        re[ii] = -q * xi;     // i*q*(xr+ixi)
        im[ii] =  q * xr;
    }
    __syncthreads();
    // inverse DIT
#pragma unroll
    for (int ls = 0; ls <= 7; ++ls) {
        int span = 1 << ls;
#pragma unroll
        for (int bi = 0; bi < 8; ++bi) {
            int bidx = bb + (bi << 4);
            int j    = bidx & (span - 1);
            int grp  = bidx >> ls;
            int p    = (grp << (ls + 1)) + j;
            int twi  = j << (7 - ls);
            int i0   = (p << 4) + el;
            int i1   = i0 + (span << 4);
            float c = twc[twi], sn = -tws[twi];   // e^{+i theta}
            float vr = re[i1], vi = im[i1];
            float tr = vr * c - vi * sn;
            float ti = vr * sn + vi * c;
            float ur = re[i0], ui = im[i0];
            re[i0] = ur + tr; im[i0] = ui + ti;
            re[i1] = ur - tr; im[i1] = ui - ti;
        }
        __syncthreads();
    }
    for (int ii = tid; ii < SEG_ * 16; ii += 256) {
        int t = ii >> 4, ee = ii & 15;
        size_t ki = ((size_t)(b * SEG_ + t)) * ED_ + e0 + ee;
        Kdy[ki] = K[ki] * re[ii] * (1.0f / 256.0f);
    }
}

// ---------------------------------------------------------------------------
// scan coefficients (N=2 states), per element
// ---------------------------------------------------------------------------
__device__ __forceinline__ void scan_coefs(float dg, float xg, float Kt, float kdy,
                                           float C0, float C1, float A0, float A1,
                                           float& dA0, float& dB0, float& dA1, float& dB1) {
    float KC0 = Kt * C0;
    float AmK0 = A0 * (1.f - KC0);
    float Ak0 = AmK0 * (1.f + KC0);
    float Bk0 = -AmK0 * Kt;
    dA0 = expf(dg * Ak0);
    dB0 = dg * Bk0 * xg + kdy;
    float KC1 = Kt * C1;
    float AmK1 = A1 * (1.f - KC1);
    float Ak1 = AmK1 * (1.f + KC1);
    float Bk1 = -AmK1 * Kt;
    dA1 = expf(dg * Ak1);
    dB1 = dg * Bk1 * xg + kdy;
}

// pass A: per-chunk (prod, local-scan) pairs
__global__ void scanA_k(const _Float16* __restrict__ delta, const _Float16* __restrict__ xs,
                        const float* __restrict__ K, const float* __restrict__ Kdy,
                        const float* __restrict__ dC, const float* __restrict__ A_log,
                        float* __restrict__ P0, float* __restrict__ P1,
                        float* __restrict__ S0, float* __restrict__ S1,
                        int layer, int s0) {
    int e = blockIdx.x * 256 + threadIdx.x;
    int b = blockIdx.y >> 4;
    int c = blockIdx.y & 15;
    float A0 = -expf(A_log[((size_t)layer * ED_ + e) * 2 + 0]);
    float A1 = -expf(A_log[((size_t)layer * ED_ + e) * 2 + 1]);
    float p0 = 1.f, p1 = 1.f, s0v = 0.f, s1v = 0.f;
    for (int tt = 0; tt < TS_; ++tt) {
        int t = c * TS_ + tt;
        size_t gi = ((size_t)(b * L_ + s0 + t)) * ED_ + e;
        size_t ki = ((size_t)(b * SEG_ + t)) * ED_ + e;
        float dg = (float)delta[gi], xg = (float)xs[gi];
        float Kt = K[ki], kdy = Kdy[ki];
        size_t ci = (size_t)(b * L_ + s0 + t) * 66 + 64;
        float C0 = dC[ci], C1 = dC[ci + 1];
        float dA0, dB0, dA1, dB1;
        scan_coefs(dg, xg, Kt, kdy, C0, C1, A0, A1, dA0, dB0, dA1, dB1);
        p0 *= dA0; s0v = dA0 * s0v + dB0;
        p1 *= dA1; s1v = dA1 * s1v + dB1;
    }
    size_t si = ((size_t)(b * CH_ + c)) * ED_ + e;
    P0[si] = p0; P1[si] = p1; S0[si] = s0v; S1[si] = s1v;
}

// pass B: sequential combine across chunks -> carry-in per chunk (h resets per segment)
__global__ void scanB_k(const float* __restrict__ P0, const float* __restrict__ P1,
                        const float* __restrict__ S0, const float* __restrict__ S1,
                        float* __restrict__ Ca0, float* __restrict__ Ca1) {
    int t = blockIdx.x * 256 + threadIdx.x;  // B*ED
    int b = t / ED_, e = t % ED_;
    float h0 = 0.f, h1 = 0.f;
    for (int c = 0; c < CH_; ++c) {
        size_t si = ((size_t)(b * CH_ + c)) * ED_ + e;
        Ca0[si] = h0; Ca1[si] = h1;
        h0 = P0[si] * h0 + S0[si];
        h1 = P1[si] * h1 + S1[si];
    }
}

// pass C: re-run recurrence from carry-in, emit y = h.C + Dp*xg  (fp16 y)
__global__ void scanC_k(const _Float16* __restrict__ delta, const _Float16* __restrict__ xs,
                        const float* __restrict__ K, const float* __restrict__ Kdy,
                        const float* __restrict__ dC, const float* __restrict__ A_log,
                        const float* __restrict__ Dp,
                        const float* __restrict__ Ca0, const float* __restrict__ Ca1,
                        _Float16* __restrict__ y, int layer, int s0) {
    int e = blockIdx.x * 256 + threadIdx.x;
    int b = blockIdx.y >> 4;
    int c = blockIdx.y & 15;
    float A0 = -expf(A_log[((size_t)layer * ED_ + e) * 2 + 0]);
    float A1 = -expf(A_log[((size_t)layer * ED_ + e) * 2 + 1]);
    float Dpe = Dp[(size_t)layer * ED_ + e];
    size_t si = ((size_t)(b * CH_ + c)) * ED_ + e;
    float h0 = Ca0[si], h1 = Ca1[si];
    for (int tt = 0; tt < TS_; ++tt) {
        int t = c * TS_ + tt;
        size_t gi = ((size_t)(b * L_ + s0 + t)) * ED_ + e;
        size_t ki = ((size_t)(b * SEG_ + t)) * ED_ + e;
        float dg = (float)delta[gi], xg = (float)xs[gi];
        float Kt = K[ki], kdy = Kdy[ki];
        size_t ci = (size_t)(b * L_ + s0 + t) * 66 + 64;
        float C0 = dC[ci], C1 = dC[ci + 1];
        float dA0, dB0, dA1, dB1;
        scan_coefs(dg, xg, Kt, kdy, C0, C1, A0, A1, dA0, dB0, dA1, dB1);
        h0 = dA0 * h0 + dB0;
        h1 = dA1 * h1 + dB1;
        y[gi] = (_Float16)(h0 * C0 + h1 * C1 + Dpe * xg);
    }
}

// ---------------------------------------------------------------------------
// gate: g = y * silu(z) -> fp16
// ---------------------------------------------------------------------------
__global__ void gate_k(const _Float16* __restrict__ y, const _Float16* __restrict__ z,
                       _Float16* __restrict__ g) {
    size_t idx = (size_t)blockIdx.x * 256 + threadIdx.x;
    g[idx] = (_Float16)((float)y[idx] * siluf((float)z[idx]));
}

// ===========================================================================
// workspace layout (bytes) — total ~238.3 MiB
// ===========================================================================
#define OFF_WK1   ((size_t)0)                   // k1_w fp16            25165824
#define OFF_WK2   (OFF_WK1 + 25165824)          // k2_w fp16            25165824
#define OFF_WK3   (OFF_WK2 + 25165824)          // k3_w fp16             8388608
#define OFF_WOUT  (OFF_WK3 + 8388608)           // out_w fp16            4194304
#define OFF_WIN   (OFF_WOUT + 4194304)          // in_w fp16 / h3 fp32   8388608 (overlay)
#define OFF_XN    (OFF_WIN + 8388608)           // xn fp16 / kerr+h1    16777216 (overlay)
#define OFF_P     (OFF_XN + 16777216)           // xs_pre->delta->gated 33554432 (fp16)
#define OFF_XS    (OFF_P + 33554432)            // xs fp16              33554432
#define OFF_Z     (OFF_XS + 33554432)           // z fp16               33554432
#define OFF_Y     (OFF_Z + 33554432)            // y fp16               33554432
#define OFF_DC    (OFF_Y + 33554432)            // dC fp32               2162688
#define OFF_H2    (OFF_DC + 2162688)            // h2 fp16               4194304
#define OFF_K     (OFF_H2 + 4194304)            // K fp32                8388608
#define OFF_KDY   (OFF_K + 8388608)             // Kdy fp32              8388608
#define OFF_SP0   (OFF_KDY + 8388608)           // scan scratch 6x524288
#define OFF_SP1   (OFF_SP0 + 524288)
#define OFF_SS0   (OFF_SP1 + 524288)
#define OFF_SS1   (OFF_SS0 + 524288)
#define OFF_SC0   (OFF_SS1 + 524288)
#define OFF_SC1   (OFF_SC0 + 524288)
#define OFF_WDT   (OFF_SC1 + 524288)            // dt_w fp16              262144
#define OFF_DR16  (OFF_WDT + 262144)            // dr fp16 [8192][64]    1048576
#define WS_NEED   (OFF_DR16 + 1048576)

extern "C" void kernel_launch(void* const* d_in, const int* in_sizes, int n_in,
                              void* d_out, int out_size, void* d_ws, size_t ws_size,
                              hipStream_t stream) {
    if (ws_size < WS_NEED) return;  // deterministic clean failure vs GPU fault

    const float* x_in   = (const float*)d_in[0];
    const float* rms_w  = (const float*)d_in[1];
    const float* in_w   = (const float*)d_in[2];
    const float* c1_w   = (const float*)d_in[3];
    const float* c1_b   = (const float*)d_in[4];
    const float* c2_w   = (const float*)d_in[5];
    const float* c2_b   = (const float*)d_in[6];
    const float* xp_w   = (const float*)d_in[7];
    const float* dt_w   = (const float*)d_in[8];
    const float* dt_b   = (const float*)d_in[9];
    const float* A_log  = (const float*)d_in[10];
    const float* Dp     = (const float*)d_in[11];
    const float* out_w  = (const float*)d_in[12];
    const float* k1_w   = (const float*)d_in[13];
    const float* k1_b   = (const float*)d_in[14];
    const float* k2_w   = (const float*)d_in[15];
    const float* k3_w   = (const float*)d_in[16];
    const float* ln_g   = (const float*)d_in[17];
    const float* ln_b   = (const float*)d_in[18];
    const float* k_alph = (const float*)d_in[19];
    const float* sigma  = (const float*)d_in[20];

    char* ws = (char*)d_ws;
    _Float16* w_k1  = (_Float16*)(ws + OFF_WK1);
    _Float16* w_k2  = (_Float16*)(ws + OFF_WK2);
    _Float16* w_k3  = (_Float16*)(ws + OFF_WK3);
    _Float16* w_out = (_Float16*)(ws + OFF_WOUT);
    _Float16* w_in  = (_Float16*)(ws + OFF_WIN);
    float*    h3buf = (float*)(ws + OFF_WIN);            // overlay (w_in dead by then)
    _Float16* xnbf  = (_Float16*)(ws + OFF_XN);
    _Float16* kerrb = (_Float16*)(ws + OFF_XN);          // overlay (xn dead)
    _Float16* h1bf  = (_Float16*)(ws + OFF_XN + 4194304);// overlay (xn dead)
    _Float16* xs_pre= (_Float16*)(ws + OFF_P);           // -> delta -> gated
    _Float16* xsbuf = (_Float16*)(ws + OFF_XS);
    _Float16* zbuf  = (_Float16*)(ws + OFF_Z);
    _Float16* ybuf  = (_Float16*)(ws + OFF_Y);
    float*    dCbuf = (float*)(ws + OFF_DC);
    _Float16* h2bf  = (_Float16*)(ws + OFF_H2);
    float*    Kbuf  = (float*)(ws + OFF_K);
    float*    Kdybuf= (float*)(ws + OFF_KDY);
    float* sP0 = (float*)(ws + OFF_SP0);
    float* sP1 = (float*)(ws + OFF_SP1);
    float* sS0 = (float*)(ws + OFF_SS0);
    float* sS1 = (float*)(ws + OFF_SS1);
    float* sC0 = (float*)(ws + OFF_SC0);
    float* sC1 = (float*)(ws + OFF_SC1);
    _Float16* w_dt  = (_Float16*)(ws + OFF_WDT);
    _Float16* dr16  = (_Float16*)(ws + OFF_DR16);
    float* dout = (float*)d_out;
    _Float16* delta = xs_pre;   // alias: xs_pre dead after conv
    _Float16* gated = xs_pre;   // alias: delta dead after segment loop

    for (int layer = 0; layer < 2; ++layer) {
        hipMemsetAsync(Kbuf, 0, (size_t)B_ * SEG_ * ED_ * 4, stream);

        // convert this layer's weights to fp16
        f2h_kernel<<<4096, 256, 0, stream>>>(in_w  + (size_t)layer * 4194304,  w_in,  1048576);
        f2h_kernel<<<12288, 256, 0, stream>>>(k1_w + (size_t)layer * 12582912, w_k1,  3145728);
        f2h_kernel<<<12288, 256, 0, stream>>>(k2_w + (size_t)layer * 12582912, w_k2,  3145728);
        f2h_kernel<<<4096, 256, 0, stream>>>(k3_w  + (size_t)layer * 4194304,  w_k3,  1048576);
        f2h_kernel<<<2048, 256, 0, stream>>>(out_w + (size_t)layer * 2097152,  w_out, 524288);
        f2h_kernel<<<128, 256, 0, stream>>>(dt_w  + (size_t)layer * 131072,   w_dt,  32768);

        const float* Hsrc = (layer == 0) ? x_in : dout;
        rmsnorm_k<<<B_ * L_, 256, 0, stream>>>(Hsrc, rms_w + (size_t)layer * DM_, xnbf);

        // xz = xn @ in_w.T -> split xs_pre | z  (M=8192, N=4096, K=1024)
        gemm_nt<128, 128, 2, 2, 1><<<dim3(32, 64), 256, 0, stream>>>(
            xnbf, w_in, 1024, 4096, nullptr, xs_pre, zbuf, nullptr, nullptr);

        convsilu_k<<<65536, 256, 0, stream>>>(xs_pre, c1_w, c1_b, c2_w, c2_b, xsbuf, layer);

        gemv_dc<<<2048, 256, 0, stream>>>(xsbuf, xp_w, dCbuf, dr16, layer);

        // delta = softplus(dr @ dt_w.T + dt_b)  (M=8192, N=2048, K=64) — MFMA
        gemm_nt<128, 128, 2, 2, 5><<<dim3(16, 64), 256, 0, stream>>>(
            dr16, w_dt, 64, 2048, nullptr, delta, nullptr,
            dt_b + (size_t)layer * ED_, nullptr);

        for (int s = 0; s < NSEG_; ++s) {
            int s0 = s * SEG_;
            kerr_k<<<8192, 256, 0, stream>>>(xsbuf, ybuf, kerrb, s0);
            // h1 = relu(Kerr @ k1.T + b1)  (1024 x 6144, K=2048)
            gemm_nt<128, 128, 2, 2, 2><<<dim3(48, 8), 256, 0, stream>>>(
                kerrb, w_k1, 2048, 6144, nullptr, h1bf, nullptr,
                k1_b + (size_t)layer * 6144, nullptr);
            // h2 = relu(h1 @ k2.T)  (1024 x 2048, K=6144)
            gemm_nt<64, 128, 1, 4, 3><<<dim3(16, 16), 256, 0, stream>>>(
                h1bf, w_k2, 6144, 2048, nullptr, h2bf, nullptr, nullptr, nullptr);
            // h3 = h2 @ k3.T  (1024 x 2048, K=2048) — fp32 into w_in overlay
            gemm_nt<64, 128, 1, 4, 0><<<dim3(16, 16), 256, 0, stream>>>(
                h2bf, w_k3, 2048, 2048, h3buf, nullptr, nullptr, nullptr, nullptr);
            ln_ema_k<<<B_ * SEG_, 256, 0, stream>>>(h3buf, ln_g, ln_b, k_alph, Kbuf, layer);
            fdu_kdy_k<<<B_ * (ED_ / 16), 256, 0, stream>>>(xsbuf, delta, Kbuf, Kdybuf,
                                                           sigma, layer, s0);
            scanA_k<<<dim3(ED_ / 256, B_ * CH_), 256, 0, stream>>>(
                delta, xsbuf, Kbuf, Kdybuf, dCbuf, A_log, sP0, sP1, sS0, sS1, layer, s0);
            scanB_k<<<(B_ * ED_) / 256, 256, 0, stream>>>(sP0, sP1, sS0, sS1, sC0, sC1);
            scanC_k<<<dim3(ED_ / 256, B_ * CH_), 256, 0, stream>>>(
                delta, xsbuf, Kbuf, Kdybuf, dCbuf, A_log, Dp, sC0, sC1, ybuf, layer, s0);
        }

        // gated = y * silu(z) -> fp16, into dead delta region
        gate_k<<<65536, 256, 0, stream>>>(ybuf, zbuf, gated);
        // out = gated @ out_w.T ; h = h_prev + out  (M=8192, N=1024, K=2048)
        gemm_nt<128, 128, 2, 2, 4><<<dim3(8, 64), 256, 0, stream>>>(
            gated, w_out, 2048, 1024, dout, nullptr, nullptr, nullptr,
            (layer == 0) ? x_in : dout);
    }
    (void)in_sizes; (void)n_in; (void)out_size;
}